// Round 1
// baseline (1794.442 us; speedup 1.0000x reference)
//
#include <hip/hip_runtime.h>

#define NGRP      65536
#define REG_STEP  0.001f      /* GROUP_REG * STEP_SIZE = 0.1 * 0.01 */
#define EPSV      1e-10f

// ---------------------------------------------------------------------------
// Pass 1: sumsq[g] += c*c  (global fp32 atomics into 256 KB L2-resident table)
// ---------------------------------------------------------------------------
__global__ __launch_bounds__(256) void GroupLasso_sumsq_kernel(
    const float4* __restrict__ c4, const int4* __restrict__ g4,
    float* __restrict__ sumsq, int n4)
{
    int stride = gridDim.x * blockDim.x;
    for (int i = blockIdx.x * blockDim.x + threadIdx.x; i < n4; i += stride) {
        float4 c = c4[i];
        int4   g = g4[i];
        atomicAdd(&sumsq[g.x], c.x * c.x);
        atomicAdd(&sumsq[g.y], c.y * c.y);
        atomicAdd(&sumsq[g.z], c.z * c.z);
        atomicAdd(&sumsq[g.w], c.w * c.w);
    }
}

// ---------------------------------------------------------------------------
// Pass 2: out[i] = c[i] * factor(groups[i]), factor computed inline
// ---------------------------------------------------------------------------
__device__ __forceinline__ float lasso_factor(float ss)
{
    float norm = sqrtf(ss);
    if (!(norm > EPSV)) return 1.0f;           // untouched tiny groups
    float s = 1.0f - REG_STEP / (norm + EPSV);
    return s > 0.0f ? s : 0.0f;
}

__global__ __launch_bounds__(256) void GroupLasso_apply_kernel(
    const float4* __restrict__ c4, const int4* __restrict__ g4,
    const float* __restrict__ sumsq, float4* __restrict__ out4, int n4)
{
    int stride = gridDim.x * blockDim.x;
    for (int i = blockIdx.x * blockDim.x + threadIdx.x; i < n4; i += stride) {
        float4 c = c4[i];
        int4   g = g4[i];
        float4 o;
        o.x = c.x * lasso_factor(sumsq[g.x]);
        o.y = c.y * lasso_factor(sumsq[g.y]);
        o.z = c.z * lasso_factor(sumsq[g.z]);
        o.w = c.w * lasso_factor(sumsq[g.w]);
        out4[i] = o;
    }
}

extern "C" void kernel_launch(void* const* d_in, const int* in_sizes, int n_in,
                              void* d_out, int out_size, void* d_ws, size_t ws_size,
                              hipStream_t stream)
{
    const float* coef   = (const float*)d_in[0];
    const int*   groups = (const int*)d_in[1];
    float*       out    = (float*)d_out;
    float*       sumsq  = (float*)d_ws;          // NGRP floats = 256 KB

    int n  = in_sizes[0];                         // 33,554,432 (divisible by 4)
    int n4 = n / 4;

    // Workspace must be zeroed every call (harness poisons it once, never
    // re-poisons between graph replays). Memset node is capture-safe.
    hipMemsetAsync(sumsq, 0, NGRP * sizeof(float), stream);

    const int block = 256;
    const int grid  = 2048;                       // 256 CU * 8 blocks, grid-stride

    GroupLasso_sumsq_kernel<<<grid, block, 0, stream>>>(
        (const float4*)coef, (const int4*)groups, sumsq, n4);

    GroupLasso_apply_kernel<<<grid, block, 0, stream>>>(
        (const float4*)coef, (const int4*)groups, sumsq, (float4*)out, n4);
}

// Round 2
// 1776.550 us; speedup vs baseline: 1.0101x; 1.0101x over previous
//
#include <hip/hip_runtime.h>

#define NGRP      65536
#define REG_STEP  0.001f      /* GROUP_REG * STEP_SIZE = 0.1 * 0.01 */
#define EPSV      1e-10f
#define MAXCOPY   8

// ---------------------------------------------------------------------------
// Pass 1: privatized sum-of-squares. Each block accumulates into one of
// `ncopy` 256 KB tables via hardware fp32 atomics (global_atomic_add_f32,
// no CAS loop).
// ---------------------------------------------------------------------------
__global__ __launch_bounds__(256) void GroupLasso_sumsq_kernel(
    const float4* __restrict__ c4, const int4* __restrict__ g4,
    float* __restrict__ tables, int ncopy, int n4)
{
    float* __restrict__ tab = tables + (size_t)(blockIdx.x % ncopy) * NGRP;
    int stride = gridDim.x * blockDim.x;
    for (int i = blockIdx.x * blockDim.x + threadIdx.x; i < n4; i += stride) {
        float4 c = c4[i];
        int4   g = g4[i];
        unsafeAtomicAdd(&tab[g.x], c.x * c.x);
        unsafeAtomicAdd(&tab[g.y], c.y * c.y);
        unsafeAtomicAdd(&tab[g.z], c.z * c.z);
        unsafeAtomicAdd(&tab[g.w], c.w * c.w);
    }
}

// ---------------------------------------------------------------------------
// Reduce copies -> final shrink factor, written in place over copy 0.
// One thread per group; each thread owns its slot, so in-place is race-free.
// ---------------------------------------------------------------------------
__global__ __launch_bounds__(256) void GroupLasso_factor_kernel(
    float* __restrict__ tables, int ncopy)
{
    int g = blockIdx.x * blockDim.x + threadIdx.x;
    if (g >= NGRP) return;
    float ss = 0.0f;
    for (int k = 0; k < ncopy; ++k)
        ss += tables[(size_t)k * NGRP + g];
    float norm = sqrtf(ss);
    float f = 1.0f;
    if (norm > EPSV) {
        float s = 1.0f - REG_STEP / (norm + EPSV);
        f = s > 0.0f ? s : 0.0f;
    }
    tables[g] = f;
}

// ---------------------------------------------------------------------------
// Pass 2: out[i] = c[i] * factor[groups[i]]  (factor table is 256 KB, L2-hot)
// ---------------------------------------------------------------------------
__global__ __launch_bounds__(256) void GroupLasso_apply_kernel(
    const float4* __restrict__ c4, const int4* __restrict__ g4,
    const float* __restrict__ factor, float4* __restrict__ out4, int n4)
{
    int stride = gridDim.x * blockDim.x;
    for (int i = blockIdx.x * blockDim.x + threadIdx.x; i < n4; i += stride) {
        float4 c = c4[i];
        int4   g = g4[i];
        float4 o;
        o.x = c.x * factor[g.x];
        o.y = c.y * factor[g.y];
        o.z = c.z * factor[g.z];
        o.w = c.w * factor[g.w];
        out4[i] = o;
    }
}

extern "C" void kernel_launch(void* const* d_in, const int* in_sizes, int n_in,
                              void* d_out, int out_size, void* d_ws, size_t ws_size,
                              hipStream_t stream)
{
    const float* coef   = (const float*)d_in[0];
    const int*   groups = (const int*)d_in[1];
    float*       out    = (float*)d_out;
    float*       tables = (float*)d_ws;

    int n  = in_sizes[0];                 // 33,554,432 (divisible by 4)
    int n4 = n / 4;

    // Privatization degree limited by workspace size; 256 KB worked before,
    // so ncopy >= 1 is guaranteed.
    int ncopy = (int)(ws_size / ((size_t)NGRP * sizeof(float)));
    if (ncopy > MAXCOPY) ncopy = MAXCOPY;
    if (ncopy < 1) ncopy = 1;

    // Zero all copies every call (ws is poisoned once, never re-poisoned).
    hipMemsetAsync(tables, 0, (size_t)ncopy * NGRP * sizeof(float), stream);

    const int block = 256;
    const int grid  = 2048;               // 256 CU * 8 blocks, grid-stride

    GroupLasso_sumsq_kernel<<<grid, block, 0, stream>>>(
        (const float4*)coef, (const int4*)groups, tables, ncopy, n4);

    GroupLasso_factor_kernel<<<NGRP / block, block, 0, stream>>>(tables, ncopy);

    GroupLasso_apply_kernel<<<grid, block, 0, stream>>>(
        (const float4*)coef, (const int4*)groups, tables, (float4*)out, n4);
}